// Round 4
// baseline (556.345 us; speedup 1.0000x reference)
//
#include <hip/hip_runtime.h>
#include <math.h>

typedef unsigned short u16;
typedef __attribute__((ext_vector_type(8))) short short8;
typedef __attribute__((ext_vector_type(4))) float f32x4;

#define AS1C(p) ((const __attribute__((address_space(1))) void*)(p))
#define AS3(p)  ((__attribute__((address_space(3))) void*)(p))

static __device__ __forceinline__ float b2f(u16 h) {
    union { unsigned u; float f; } c; c.u = ((unsigned)h) << 16; return c.f;
}
static __device__ __forceinline__ u16 f2b(float f) {
    union { float f; unsigned u; } c; c.f = f;
    unsigned r = c.u + 0x7FFFu + ((c.u >> 16) & 1u);
    return (u16)(r >> 16);
}

// Epilogue modes (runtime)
#define EP_NONE     0
#define EP_RELU     1
#define EP_SIGMOID  2
#define EP_TANH_MUL 3   // out = tanh(acc+bias) * auxf[R,C]
#define EP_TANH_ADD 4   // out = auxf[R,C] + tanh(acc+bias)
#define EP_DIAG     5   // out = acc; if (R==C) += 0.9*tanh(auxf[R])

struct GDesc {
    const u16* A;       // [M, lda] bf16
    const u16* W;       // [N, K] bf16 dense
    const float* bias;  // [N] fp32 or null
    const float* auxf;  // fp32 aux (per-ep meaning) or null
    u16* outb;          // bf16 out, row stride ldd
    float* outf;        // fp32 out [M,N] dense, or null
    int lda, ldd, N, K, ep, nbm;
};

struct GArgs { GDesc d0, d1, d2; int s1, s2; };

// 256x256 tile, BK=64, 512 threads = 8 waves (2 row-groups x 4 col-groups).
// Double-buffered LDS (128 KB), stage-next-before-compute, one raw barrier +
// vmcnt(0) per K-tile. LDS 16B-slot swizzle: slot ^= (row & 7), applied on the
// GLOBAL source side at staging (linear global_load_lds dest) and on ds_read.
__global__ __launch_bounds__(512, 2)
void gemm256(GArgs ga)
{
    __shared__ __align__(16) u16 LDS[65536];   // 2 bufs x (A 256x64 + B 256x64)

    const int bid = (int)blockIdx.x;
    GDesc dd = (bid < ga.s1) ? ga.d0 : ((bid < ga.s2) ? ga.d1 : ga.d2);
    const int b = bid - ((bid < ga.s1) ? 0 : ((bid < ga.s2) ? ga.s1 : ga.s2));

    const int tid  = threadIdx.x;       // 0..511
    const int lane = tid & 63;
    const int wid  = tid >> 6;          // 0..7
    const int wr   = wid >> 2;          // 0..1  (row half of block tile)
    const int wc   = wid & 3;           // 0..3  (col quarter)

    const int bm = b % dd.nbm;
    const int bn = b / dd.nbm;
    const int lda = dd.lda, K = dd.K, N = dd.N, ldd = dd.ldd;

    // ---- staging coords: thread covers LDS row (tid>>3), 16B slot (tid&7).
    // Source column pre-swizzled so that swizzled ds_read sees natural data.
    const int srow  = tid >> 3;                       // 0..63 (per 64-row sweep)
    const int sslot = tid & 7;
    const int sgcol = (sslot ^ (srow & 7)) * 8;       // bf16 units
    const u16* Abase = dd.A + (size_t)(bm * 256 + srow) * lda + sgcol;
    const u16* Wbase = dd.W + (size_t)(bn * 256 + srow) * K + sgcol;
    const int ldst = tid * 8;                         // linear LDS dest (u16), +j*4096

    f32x4 acc[8][4];
#pragma unroll
    for (int m = 0; m < 8; ++m)
#pragma unroll
        for (int n = 0; n < 4; ++n) acc[m][n] = (f32x4){0.f, 0.f, 0.f, 0.f};

    const int nkt = K >> 6;

#define STAGE(bufi, kt)                                                          \
    {                                                                            \
        const int k0_ = (kt) << 6;                                               \
        u16* al_ = &LDS[(bufi) * 32768 + ldst];                                  \
        u16* bl_ = &LDS[(bufi) * 32768 + 16384 + ldst];                          \
        _Pragma("unroll")                                                        \
        for (int j = 0; j < 4; ++j)                                              \
            __builtin_amdgcn_global_load_lds(AS1C(Abase + (size_t)j * 64 * lda + k0_), \
                                             AS3(al_ + j * 4096), 16, 0, 0);     \
        _Pragma("unroll")                                                        \
        for (int j = 0; j < 4; ++j)                                              \
            __builtin_amdgcn_global_load_lds(AS1C(Wbase + (size_t)j * 64 * K + k0_),   \
                                             AS3(bl_ + j * 4096), 16, 0, 0);     \
    }

#define WAITBAR()                                                                \
    {                                                                            \
        asm volatile("s_waitcnt vmcnt(0)" ::: "memory");                         \
        __builtin_amdgcn_sched_barrier(0);                                       \
        __builtin_amdgcn_s_barrier();                                            \
        __builtin_amdgcn_sched_barrier(0);                                       \
    }

    // fragment-read swizzle constants (row&7 == lane&7 for all our frag rows)
    const int swz = (lane & 7) << 4;            // byte XOR
    const int cnat = (lane >> 4) << 4;          // natural byte col base (0,16,32,48)

    short8 AF0[4][2], AF1[4][2], BF[2][2];

#define LDA_SET(AF, rh, Al)                                                      \
    {                                                                            \
        const int rb_ = wr * 128 + (rh) * 64 + (lane & 15);                      \
        _Pragma("unroll")                                                        \
        for (int mm = 0; mm < 4; ++mm) {                                         \
            const u16* rp_ = (Al) + (rb_ + mm * 16) * 64;                        \
            _Pragma("unroll")                                                    \
            for (int ks = 0; ks < 2; ++ks)                                       \
                AF[mm][ks] = *(const short8*)(rp_ + ((((ks << 6) | cnat) ^ swz) >> 1)); \
        }                                                                        \
    }

#define LDB_SET(ch, Bl)                                                          \
    {                                                                            \
        const int rb_ = wc * 64 + (ch) * 32 + (lane & 15);                       \
        _Pragma("unroll")                                                        \
        for (int nn = 0; nn < 2; ++nn) {                                         \
            const u16* rp_ = (Bl) + (rb_ + nn * 16) * 64;                        \
            _Pragma("unroll")                                                    \
            for (int ks = 0; ks < 2; ++ks)                                       \
                BF[nn][ks] = *(const short8*)(rp_ + ((((ks << 6) | cnat) ^ swz) >> 1)); \
        }                                                                        \
    }

#define QMFMA(AF, rh, ch)                                                        \
    {                                                                            \
        __builtin_amdgcn_s_setprio(1);                                           \
        _Pragma("unroll")                                                        \
        for (int mm = 0; mm < 4; ++mm)                                           \
            _Pragma("unroll")                                                    \
            for (int nn = 0; nn < 2; ++nn)                                       \
                _Pragma("unroll")                                                \
                for (int ks = 0; ks < 2; ++ks)                                   \
                    acc[(rh) * 4 + mm][(ch) * 2 + nn] =                          \
                        __builtin_amdgcn_mfma_f32_16x16x32_bf16(                 \
                            AF[mm][ks], BF[nn][ks], acc[(rh) * 4 + mm][(ch) * 2 + nn], 0, 0, 0); \
        __builtin_amdgcn_s_setprio(0);                                           \
    }

    STAGE(0, 0);
    WAITBAR();

    int buf = 0;
    for (int kt = 0; kt < nkt; ++kt) {
        if (kt + 1 < nkt) STAGE(buf ^ 1, kt + 1);
        const u16* Al = &LDS[buf * 32768];
        const u16* Bl = Al + 16384;
        // snake order: (0,0) -> (1,0) -> (1,1) -> (0,1); AF0 held across.
        LDA_SET(AF0, 0, Al);
        LDB_SET(0, Bl);
        QMFMA(AF0, 0, 0);
        LDA_SET(AF1, 1, Al);
        QMFMA(AF1, 1, 0);
        LDB_SET(1, Bl);
        QMFMA(AF1, 1, 1);
        QMFMA(AF0, 0, 1);
        WAITBAR();
        buf ^= 1;
    }

#undef STAGE
#undef WAITBAR
#undef LDA_SET
#undef LDB_SET
#undef QMFMA

    // epilogue: D layout col=lane&15, row=(lane>>4)*4+j
    const int rbase = bm * 256 + wr * 128 + (lane >> 4) * 4;
    const int cbase = bn * 256 + wc * 64 + (lane & 15);
    const int ep = dd.ep;
#pragma unroll
    for (int n = 0; n < 4; ++n) {
        const int C = cbase + n * 16;
        const float bv = dd.bias ? dd.bias[C] : 0.f;
#pragma unroll
        for (int m = 0; m < 8; ++m) {
            const int R0 = rbase + m * 16;
#pragma unroll
            for (int j = 0; j < 4; ++j) {
                const int R = R0 + j;
                float v = acc[m][n][j] + bv;
                if (ep == EP_RELU)          v = fmaxf(v, 0.f);
                else if (ep == EP_SIGMOID)  v = 1.f / (1.f + expf(-v));
                else if (ep == EP_TANH_MUL) v = tanhf(v) * dd.auxf[(size_t)R * N + C];
                else if (ep == EP_TANH_ADD) v = dd.auxf[(size_t)R * N + C] + tanhf(v);
                else if (ep == EP_DIAG)     { if (R == C) v += 0.9f * tanhf(dd.auxf[R]); }
                dd.outb[(size_t)R * ldd + C] = f2b(v);
                if (dd.outf) dd.outf[(size_t)R * N + C] = v;
            }
        }
    }
}

// In-place LayerNorm over D=1024 bf16 (+optional ReLU). gam/bet fp32.
template<bool RELU>
__global__ __launch_bounds__(256)
void ln1024(u16* __restrict__ X, const float* __restrict__ gam, const float* __restrict__ bet)
{
    const int row = blockIdx.x;
    u16* xp = X + (size_t)row * 1024 + threadIdx.x * 4;
    u16 loc[4];
    *(uint2*)loc = *(const uint2*)xp;
    float x0 = b2f(loc[0]), x1 = b2f(loc[1]), x2 = b2f(loc[2]), x3 = b2f(loc[3]);
    float s = x0 + x1 + x2 + x3;
    float q = x0 * x0 + x1 * x1 + x2 * x2 + x3 * x3;
#pragma unroll
    for (int off = 32; off; off >>= 1) { s += __shfl_xor(s, off); q += __shfl_xor(q, off); }
    __shared__ float sm[8];
    const int wave = threadIdx.x >> 6, lane = threadIdx.x & 63;
    if (lane == 0) { sm[wave] = s; sm[4 + wave] = q; }
    __syncthreads();
    s = sm[0] + sm[1] + sm[2] + sm[3];
    q = sm[4] + sm[5] + sm[6] + sm[7];
    const float mean = s * (1.f / 1024.f);
    const float var  = q * (1.f / 1024.f) - mean * mean;
    const float inv  = rsqrtf(var + 1e-5f);
    const int cb = threadIdx.x * 4;
#pragma unroll
    for (int j = 0; j < 4; ++j) {
        float y = (b2f(loc[j]) - mean) * inv * gam[cb + j] + bet[cb + j];
        if (RELU) y = fmaxf(y, 0.f);
        loc[j] = f2b(y);
    }
    *(uint2*)xp = *(uint2*)loc;
}

// s_t = LN(s_prev + g*pm + (1-g)*wm) over D=1024. sp fp32, g/pm/wm bf16, out fp32.
__global__ __launch_bounds__(256)
void mix_ln(const float* __restrict__ sp, const u16* __restrict__ gt,
            const u16* __restrict__ pm, const u16* __restrict__ wm,
            const float* __restrict__ og, const float* __restrict__ ob,
            float* __restrict__ out)
{
    const int row = blockIdx.x;
    const size_t base = (size_t)row * 1024 + threadIdx.x * 4;
    float4 lsp = *(const float4*)(sp + base);
    u16 lg[4], lp[4], lw[4];
    *(uint2*)lg = *(const uint2*)(gt + base);
    *(uint2*)lp = *(const uint2*)(pm + base);
    *(uint2*)lw = *(const uint2*)(wm + base);
    float x[4];
    const float* lspp = (const float*)&lsp;
#pragma unroll
    for (int j = 0; j < 4; ++j) {
        float g = b2f(lg[j]);
        x[j] = lspp[j] + g * b2f(lp[j]) + (1.f - g) * b2f(lw[j]);
    }
    float s = x[0] + x[1] + x[2] + x[3];
    float q = x[0]*x[0] + x[1]*x[1] + x[2]*x[2] + x[3]*x[3];
#pragma unroll
    for (int off = 32; off; off >>= 1) { s += __shfl_xor(s, off); q += __shfl_xor(q, off); }
    __shared__ float sm[8];
    const int wave = threadIdx.x >> 6, lane = threadIdx.x & 63;
    if (lane == 0) { sm[wave] = s; sm[4 + wave] = q; }
    __syncthreads();
    s = sm[0] + sm[1] + sm[2] + sm[3];
    q = sm[4] + sm[5] + sm[6] + sm[7];
    const float mean = s * (1.f / 1024.f);
    const float var  = q * (1.f / 1024.f) - mean * mean;
    const float inv  = rsqrtf(var + 1e-5f);
    const int cb = threadIdx.x * 4;
    float4 o;
    float* op = (float*)&o;
#pragma unroll
    for (int j = 0; j < 4; ++j)
        op[j] = (x[j] - mean) * inv * og[cb + j] + ob[cb + j];
    *(float4*)(out + base) = o;
}

// Batched strided copy/convert: fp32->bf16 or bf16->bf16, 8 elems/thread.
struct CDesc { const void* src; u16* dst; int srcCols8; int dstStride; int dstOff; unsigned end; int isbf16; };
struct CArgs { CDesc d[16]; unsigned total; };

__global__ __launch_bounds__(256)
void multi_copy(CArgs ca)
{
    const unsigned idx = blockIdx.x * 256 + threadIdx.x;
    if (idx >= ca.total) return;
    int i = 0; unsigned start = 0;
    while (idx >= ca.d[i].end) { start = ca.d[i].end; ++i; }
    const CDesc cd = ca.d[i];
    const unsigned local = idx - start;
    const int r = local / cd.srcCols8;
    const int c = local % cd.srcCols8;
    u16 o[8];
    if (cd.isbf16) {
        *(uint4*)o = *(const uint4*)((const u16*)cd.src + ((size_t)r * cd.srcCols8 + c) * 8);
    } else {
        const float* s = (const float*)cd.src + ((size_t)r * cd.srcCols8 + c) * 8;
        const float4 a = *(const float4*)s;
        const float4 bq = *(const float4*)(s + 4);
        const float* ap = (const float*)&a;
        const float* bp = (const float*)&bq;
#pragma unroll
        for (int j = 0; j < 4; ++j) { o[j] = f2b(ap[j]); o[4 + j] = f2b(bp[j]); }
    }
    *(uint4*)(cd.dst + (size_t)r * cd.dstStride + cd.dstOff + (size_t)c * 8) = *(uint4*)o;
}

extern "C" void kernel_launch(void* const* d_in, const int* in_sizes, int n_in,
                              void* d_out, int out_size, void* d_ws, size_t ws_size,
                              hipStream_t stream)
{
    const float* s_prev = (const float*)d_in[0];
    const float* w_prev = (const float*)d_in[1];
    const float* p_prev = (const float*)d_in[2];
    const float* e_t    = (const float*)d_in[3];
    const float* c_t    = (const float*)d_in[4];
    const float* fw1    = (const float*)d_in[5];
    const float* fb1    = (const float*)d_in[6];
    const float* fln_g  = (const float*)d_in[7];
    const float* fln_b  = (const float*)d_in[8];
    const float* fw2    = (const float*)d_in[9];
    const float* fb2    = (const float*)d_in[10];
    const float* A_diag = (const float*)d_in[11];
    const float* A_U    = (const float*)d_in[12];
    const float* A_V    = (const float*)d_in[13];
    const float* amod_w = (const float*)d_in[14];
    const float* amod_b = (const float*)d_in[15];
    const float* bnet_w = (const float*)d_in[16];
    const float* bnet_b = (const float*)d_in[17];
    const float* pw1    = (const float*)d_in[18];
    const float* pb1    = (const float*)d_in[19];
    const float* pln_g  = (const float*)d_in[20];
    const float* pln_b  = (const float*)d_in[21];
    const float* pw2    = (const float*)d_in[22];
    const float* pb2    = (const float*)d_in[23];
    const float* pw3    = (const float*)d_in[24];
    const float* pb3    = (const float*)d_in[25];
    const float* gw     = (const float*)d_in[26];
    const float* gb     = (const float*)d_in[27];
    const float* uw     = (const float*)d_in[28];
    const float* up     = (const float*)d_in[29];
    const float* oln_g  = (const float*)d_in[30];
    const float* oln_b  = (const float*)d_in[31];

    float* out_s = (float*)d_out;                    // [8192,1024]
    float* out_w = out_s + (size_t)8192 * 1024;      // [8192,1024]
    float* out_p = out_w + (size_t)8192 * 1024;      // [8192,512]

    u16* ws = (u16*)d_ws;
    u16* FIN  = ws;                    // [8192,2560]; later PIN [8192,1536] at base
    u16* W_bf = ws + 12582912;         // [8192,1024]
    u16* H    = ws + 20971520;         // [8192,1024]; later P_bf [8192,512]
    u16* P_bf = H;
    u16* Z    = ws + 29360128;         // [8192,512]
    u16* G    = ws + 33554432;         // [8192,1024]
    u16* ACAT = ws + 41943040;         // [8192,2048]; later PM/WM
    u16* PM   = ACAT;
    u16* WM   = ACAT + 8388608;
    u16* WCAT = ws + 58720256;         // [1024,2048]
    u16* wb   = ws + 60817408;         // bf16 weights pool
    u16* fw1b  = wb;
    u16* gwb   = wb + 2621440;
    u16* fw2b  = wb + 5242880;
    u16* amodb = wb + 5767168;
    u16* pw1b  = wb + 6291456;
    u16* pw2b  = wb + 7864320;
    u16* pw3b  = wb + 8388608;
    u16* uwb   = wb + 8650752;
    u16* upb   = wb + 9699328;
    u16* AUb   = wb + 10223616;
    u16* AVb   = wb + 10485760;        // pool ends ws+10,747,904

    const dim3 blk(256);
    const dim3 blk512(512);

    // ---------- batch 1: weight cvts + FIN assembly + c_t->ACAT + bnet_w->WCAT
    {
        CArgs ca; unsigned cum = 0; int nd = 0;
        auto push = [&](const void* src, u16* dst, int cols8, int stride, int off,
                        int rows, int isbf) {
            cum += (unsigned)rows * cols8;
            ca.d[nd++] = CDesc{src, dst, cols8, stride, off, cum, isbf};
        };
        push(fw1,    fw1b,  320, 2560, 0,    1024, 0);
        push(gw,     gwb,   320, 2560, 0,    1024, 0);
        push(fw2,    fw2b,  128, 1024, 0,    512,  0);
        push(amod_w, amodb, 64,  512,  0,    1024, 0);
        push(pw1,    pw1b,  192, 1536, 0,    1024, 0);
        push(pw2,    pw2b,  128, 1024, 0,    512,  0);
        push(pw3,    pw3b,  64,  512,  0,    512,  0);
        push(uw,     uwb,   128, 1024, 0,    1024, 0);
        push(up,     upb,   64,  512,  0,    1024, 0);
        push(A_U,    AUb,   32,  256,  0,    1024, 0);
        push(A_V,    AVb,   32,  256,  0,    1024, 0);
        push(s_prev, FIN,   128, 2560, 0,    8192, 0);
        push(e_t,    FIN,   128, 2560, 1024, 8192, 0);
        push(c_t,    FIN,   64,  2560, 2048, 8192, 0);
        push(c_t,    ACAT,  64,  2048, 1024, 8192, 0);
        push(bnet_w, WCAT,  128, 2048, 1024, 1024, 0);
        ca.total = cum;
        multi_copy<<<dim3((cum + 255) / 256), blk, 0, stream>>>(ca);
    }

    // ---------- fused GEMM 1: fw1 (H) || gate (G) -> 256 blocks
    {
        GArgs ga;
        ga.d0 = GDesc{FIN, fw1b, fb1, nullptr, H, nullptr, 2560, 1024, 1024, 2560, EP_NONE,    32};
        ga.d1 = GDesc{FIN, gwb,  gb,  nullptr, G, nullptr, 2560, 1024, 1024, 2560, EP_SIGMOID, 32};
        ga.d2 = ga.d1; ga.s1 = 128; ga.s2 = 256;
        gemm256<<<dim3(256), blk512, 0, stream>>>(ga);
    }
    ln1024<true><<<8192, blk, 0, stream>>>(H, fln_g, fln_b);

    // ---------- fused GEMM 2: fw2 (Z) || amod (ACAT) || A_base (WCAT) -> 208 blocks
    {
        GArgs ga;
        ga.d0 = GDesc{H,          fw2b,  fb2,     nullptr, Z,    nullptr, 1024, 512,  512,  1024, EP_NONE,     32};
        ga.d1 = GDesc{FIN + 2048, amodb, amod_b,  w_prev,  ACAT, nullptr, 2560, 2048, 1024, 512,  EP_TANH_MUL, 32};
        ga.d2 = GDesc{AUb,        AVb,   nullptr, A_diag,  WCAT, nullptr, 256,  2048, 1024, 256,  EP_DIAG,     4};
        ga.s1 = 64; ga.s2 = 192;
        gemm256<<<dim3(208), blk512, 0, stream>>>(ga);
    }

    // ---------- batch 2: PIN = [p_prev || z || c_t] at FIN base; Z -> ACAT col 1536
    {
        CArgs ca; unsigned cum = 0; int nd = 0;
        auto push = [&](const void* src, u16* dst, int cols8, int stride, int off,
                        int rows, int isbf) {
            cum += (unsigned)rows * cols8;
            ca.d[nd++] = CDesc{src, dst, cols8, stride, off, cum, isbf};
        };
        push(p_prev, FIN,  64, 1536, 0,    8192, 0);
        push(Z,      FIN,  64, 1536, 512,  8192, 1);
        push(c_t,    FIN,  64, 1536, 1024, 8192, 0);
        push(Z,      ACAT, 64, 2048, 1536, 8192, 1);
        ca.total = cum;
        multi_copy<<<dim3((cum + 255) / 256), blk, 0, stream>>>(ca);
    }

    // ---------- fused GEMM 3: w_t (ACAT@WCAT^T) || pw1 (PIN) -> 256 blocks
    {
        GArgs ga;
        ga.d0 = GDesc{ACAT, WCAT, bnet_b, nullptr, W_bf, out_w,   2048, 1024, 1024, 2048, EP_NONE, 32};
        ga.d1 = GDesc{FIN,  pw1b, pb1,    nullptr, H,    nullptr, 1536, 1024, 1024, 1536, EP_NONE, 32};
        ga.d2 = ga.d1; ga.s1 = 128; ga.s2 = 256;
        gemm256<<<dim3(256), blk512, 0, stream>>>(ga);
    }
    ln1024<true><<<8192, blk, 0, stream>>>(H, pln_g, pln_b);

    // ---------- fused GEMM 4: pw2 (H -> Z, relu) || uw (W_bf -> WM) -> 192 blocks
    {
        GArgs ga;
        ga.d0 = GDesc{H,    pw2b, pb2,     nullptr, Z,  nullptr, 1024, 512,  512,  1024, EP_RELU, 32};
        ga.d1 = GDesc{W_bf, uwb,  nullptr, nullptr, WM, nullptr, 1024, 1024, 1024, 1024, EP_NONE, 32};
        ga.d2 = ga.d1; ga.s1 = 64; ga.s2 = 192;
        gemm256<<<dim3(192), blk512, 0, stream>>>(ga);
    }

    // ---------- pw3: p_t = p_prev + tanh(Z@pw3^T + pb3) -> P_bf + out_p
    {
        GArgs ga;
        ga.d0 = GDesc{Z, pw3b, pb3, p_prev, P_bf, out_p, 512, 512, 512, 512, EP_TANH_ADD, 32};
        ga.d1 = ga.d0; ga.d2 = ga.d0; ga.s1 = 64; ga.s2 = 64;
        gemm256<<<dim3(64), blk512, 0, stream>>>(ga);
    }

    // ---------- up: pm = P_bf @ up^T -> PM
    {
        GArgs ga;
        ga.d0 = GDesc{P_bf, upb, nullptr, nullptr, PM, nullptr, 512, 1024, 1024, 512, EP_NONE, 32};
        ga.d1 = ga.d0; ga.d2 = ga.d0; ga.s1 = 128; ga.s2 = 128;
        gemm256<<<dim3(128), blk512, 0, stream>>>(ga);
    }

    mix_ln<<<8192, blk, 0, stream>>>(s_prev, G, PM, WM, oln_g, oln_b, out_s);
}

// Round 5
// 463.004 us; speedup vs baseline: 1.2016x; 1.2016x over previous
//
#include <hip/hip_runtime.h>
#include <math.h>

typedef unsigned short u16;
typedef __attribute__((ext_vector_type(8))) short short8;
typedef __attribute__((ext_vector_type(4))) float f32x4;

#define AS1C(p) ((const __attribute__((address_space(1))) void*)(p))
#define AS3(p)  ((__attribute__((address_space(3))) void*)(p))

static __device__ __forceinline__ float b2f(u16 h) {
    union { unsigned u; float f; } c; c.u = ((unsigned)h) << 16; return c.f;
}
static __device__ __forceinline__ u16 f2b(float f) {
    union { float f; unsigned u; } c; c.f = f;
    unsigned r = c.u + 0x7FFFu + ((c.u >> 16) & 1u);
    return (u16)(r >> 16);
}

// Epilogue modes (runtime)
#define EP_NONE     0
#define EP_RELU     1
#define EP_SIGMOID  2
#define EP_TANH_MUL 3   // out = tanh(acc+bias) * auxf[R,C]
#define EP_TANH_ADD 4   // out = auxf[R,C] + tanh(acc+bias)
#define EP_DIAG     5   // out = acc; if (R==C) += 0.9*tanh(auxf[R])

struct GDesc {
    const u16* A;       // [M, lda] bf16
    const u16* W;       // [N, K] bf16 dense
    const float* bias;  // [N] fp32 or null
    const float* auxf;  // fp32 aux (per-ep meaning) or null
    u16* outb;          // bf16 out, row stride ldd
    float* outf;        // fp32 out [M,N] dense, or null
    int lda, ldd, N, K, ep, nbm;
};

struct GArgs { GDesc d0, d1, d2; int s1, s2; };

// BM=256 x BN=128 tile, BK=64. 512 threads = 8 waves (4M x 2N), wave-out 64x64.
// LDS: A double-buffer (2 x 32KB) + B ring-of-4 (4 x 16KB) = 128KB.
// Counted-vmcnt pipeline: per iter stage A(kt+1) [4 loads] + B(kt+3) [2 loads],
// one raw s_barrier per iter with s_waitcnt vmcnt(2) (B-stage loads stay in
// flight across the barrier; never drains to 0 in steady state).
// LDS 16B-slot swizzle (slot ^= row&7) applied on the pre-swizzled GLOBAL
// source at staging + on ds_read (both-sides; zero bank conflicts, R4-proven).
// REQUIRES K % 64 == 0 and K >= 256 (nkt >= 4).
__global__ __launch_bounds__(512, 2)
void gemm_p(GArgs ga)
{
    __shared__ __align__(16) u16 LDS[65536];   // A: [0,32768) dbuf; B: [32768,65536) ring4

    const int bid = (int)blockIdx.x;
    GDesc dd = (bid < ga.s1) ? ga.d0 : ((bid < ga.s2) ? ga.d1 : ga.d2);
    const int b = bid - ((bid < ga.s1) ? 0 : ((bid < ga.s2) ? ga.s1 : ga.s2));

    const int tid  = threadIdx.x;       // 0..511
    const int lane = tid & 63;
    const int wid  = tid >> 6;          // 0..7
    const int wr   = wid >> 1;          // 0..3 (64-row slice)
    const int wc   = wid & 1;           // 0..1 (64-col slice)

    const int bm = b % dd.nbm;
    const int bn = b / dd.nbm;
    const int lda = dd.lda, K = dd.K, N = dd.N, ldd = dd.ldd;
    const int nkt = K >> 6;

    // staging: thread covers row (tid>>3) (+64 per sweep), 16B slot (tid&7);
    // global source column pre-swizzled so swizzled ds_read sees natural data.
    const int srow  = tid >> 3;                       // 0..63
    const int sslot = tid & 7;
    const int sgcol = (sslot ^ (srow & 7)) * 8;       // u16 units
    const u16* Ag = dd.A + (size_t)(bm * 256 + srow) * lda + sgcol;
    const u16* Wg = dd.W + (size_t)(bn * 128 + srow) * K + sgcol;
    const int ldst = tid * 8;                         // linear LDS dest (u16)

    f32x4 acc[4][4];
#pragma unroll
    for (int m = 0; m < 4; ++m)
#pragma unroll
        for (int n = 0; n < 4; ++n) acc[m][n] = (f32x4){0.f, 0.f, 0.f, 0.f};

#define STAGE_A(bufi, kt)                                                        \
    {                                                                            \
        const int k0_ = (kt) << 6;                                               \
        u16* d_ = &LDS[(bufi) * 16384 + ldst];                                   \
        _Pragma("unroll")                                                        \
        for (int j = 0; j < 4; ++j)                                              \
            __builtin_amdgcn_global_load_lds(AS1C(Ag + (size_t)(j * 64) * lda + k0_), \
                                             AS3(d_ + j * 4096), 16, 0, 0);      \
    }
#define STAGE_B(sloti, kt)                                                       \
    {                                                                            \
        const int k0_ = (kt) << 6;                                               \
        u16* d_ = &LDS[32768 + (sloti) * 8192 + ldst];                           \
        _Pragma("unroll")                                                        \
        for (int j = 0; j < 2; ++j)                                              \
            __builtin_amdgcn_global_load_lds(AS1C(Wg + (size_t)(j * 64) * K + k0_),   \
                                             AS3(d_ + j * 4096), 16, 0, 0);      \
    }

    // fragment-read swizzle constants (frag row ≡ lane (mod 8))
    const int swz  = (lane & 7) << 4;           // byte XOR
    const int cnat = (lane >> 4) << 4;          // natural byte col base (0,16,32,48)

    // ---- prologue: A(0), B(0..2); wait A(0)+B(0) (allow B(1),B(2) in flight)
    STAGE_A(0, 0);
    __builtin_amdgcn_sched_barrier(0);
    STAGE_B(0, 0);
    STAGE_B(1, 1);
    STAGE_B(2, 2);
    __builtin_amdgcn_sched_barrier(0);
    asm volatile("s_waitcnt vmcnt(4)" ::: "memory");
    __builtin_amdgcn_sched_barrier(0);
    __builtin_amdgcn_s_barrier();
    __builtin_amdgcn_sched_barrier(0);

    for (int kt = 0; kt < nkt; ++kt) {
        const int abuf = kt & 1;
        // clamped sources keep issue counts uniform; dead slots never re-read
        const int ka = (kt + 1 < nkt) ? kt + 1 : nkt - 1;
        const int kb = (kt + 3 < nkt) ? kt + 3 : nkt - 1;
        STAGE_A(abuf ^ 1, ka);
        __builtin_amdgcn_sched_barrier(0);
        STAGE_B((kt + 3) & 3, kb);
        __builtin_amdgcn_sched_barrier(0);

        const u16* Al = &LDS[abuf * 16384];
        const u16* Bl = &LDS[32768 + (kt & 3) * 8192];

        short8 af[4][2], bf[4][2];
#pragma unroll
        for (int m = 0; m < 4; ++m) {
            const u16* rp = Al + (wr * 64 + m * 16 + (lane & 15)) * 64;
#pragma unroll
            for (int ks = 0; ks < 2; ++ks)
                af[m][ks] = *(const short8*)(rp + ((((ks << 6) | cnat) ^ swz) >> 1));
        }
#pragma unroll
        for (int n = 0; n < 4; ++n) {
            const u16* rp = Bl + (wc * 64 + n * 16 + (lane & 15)) * 64;
#pragma unroll
            for (int ks = 0; ks < 2; ++ks)
                bf[n][ks] = *(const short8*)(rp + ((((ks << 6) | cnat) ^ swz) >> 1));
        }

        __builtin_amdgcn_s_setprio(1);
#pragma unroll
        for (int m = 0; m < 4; ++m)
#pragma unroll
            for (int n = 0; n < 4; ++n)
#pragma unroll
                for (int ks = 0; ks < 2; ++ks)
                    acc[m][n] = __builtin_amdgcn_mfma_f32_16x16x32_bf16(
                        af[m][ks], bf[n][ks], acc[m][n], 0, 0, 0);
        __builtin_amdgcn_s_setprio(0);

        __builtin_amdgcn_sched_barrier(0);
        asm volatile("s_waitcnt vmcnt(2)" ::: "memory");
        __builtin_amdgcn_sched_barrier(0);
        __builtin_amdgcn_s_barrier();
        __builtin_amdgcn_sched_barrier(0);
    }

#undef STAGE_A
#undef STAGE_B

    // epilogue: D layout col=lane&15, row=(lane>>4)*4+j
    const int rbase = bm * 256 + wr * 64 + (lane >> 4) * 4;
    const int cbase = bn * 128 + wc * 64 + (lane & 15);
    const int ep = dd.ep;
#pragma unroll
    for (int n = 0; n < 4; ++n) {
        const int C = cbase + n * 16;
        const float bv = dd.bias ? dd.bias[C] : 0.f;
#pragma unroll
        for (int m = 0; m < 4; ++m) {
            const int R0 = rbase + m * 16;
#pragma unroll
            for (int j = 0; j < 4; ++j) {
                const int R = R0 + j;
                float v = acc[m][n][j] + bv;
                if (ep == EP_RELU)          v = fmaxf(v, 0.f);
                else if (ep == EP_SIGMOID)  v = 1.f / (1.f + expf(-v));
                else if (ep == EP_TANH_MUL) v = tanhf(v) * dd.auxf[(size_t)R * N + C];
                else if (ep == EP_TANH_ADD) v = dd.auxf[(size_t)R * N + C] + tanhf(v);
                else if (ep == EP_DIAG)     { if (R == C) v += 0.9f * tanhf(dd.auxf[R]); }
                dd.outb[(size_t)R * ldd + C] = f2b(v);
                if (dd.outf) dd.outf[(size_t)R * N + C] = v;
            }
        }
    }
}

// In-place LayerNorm over D=1024 bf16 (+optional ReLU). gam/bet fp32.
template<bool RELU>
__global__ __launch_bounds__(256)
void ln1024(u16* __restrict__ X, const float* __restrict__ gam, const float* __restrict__ bet)
{
    const int row = blockIdx.x;
    u16* xp = X + (size_t)row * 1024 + threadIdx.x * 4;
    u16 loc[4];
    *(uint2*)loc = *(const uint2*)xp;
    float x0 = b2f(loc[0]), x1 = b2f(loc[1]), x2 = b2f(loc[2]), x3 = b2f(loc[3]);
    float s = x0 + x1 + x2 + x3;
    float q = x0 * x0 + x1 * x1 + x2 * x2 + x3 * x3;
#pragma unroll
    for (int off = 32; off; off >>= 1) { s += __shfl_xor(s, off); q += __shfl_xor(q, off); }
    __shared__ float sm[8];
    const int wave = threadIdx.x >> 6, lane = threadIdx.x & 63;
    if (lane == 0) { sm[wave] = s; sm[4 + wave] = q; }
    __syncthreads();
    s = sm[0] + sm[1] + sm[2] + sm[3];
    q = sm[4] + sm[5] + sm[6] + sm[7];
    const float mean = s * (1.f / 1024.f);
    const float var  = q * (1.f / 1024.f) - mean * mean;
    const float inv  = rsqrtf(var + 1e-5f);
    const int cb = threadIdx.x * 4;
#pragma unroll
    for (int j = 0; j < 4; ++j) {
        float y = (b2f(loc[j]) - mean) * inv * gam[cb + j] + bet[cb + j];
        if (RELU) y = fmaxf(y, 0.f);
        loc[j] = f2b(y);
    }
    *(uint2*)xp = *(uint2*)loc;
}

// s_t = LN(s_prev + g*pm + (1-g)*wm) over D=1024. sp fp32, g/pm/wm bf16, out fp32.
__global__ __launch_bounds__(256)
void mix_ln(const float* __restrict__ sp, const u16* __restrict__ gt,
            const u16* __restrict__ pm, const u16* __restrict__ wm,
            const float* __restrict__ og, const float* __restrict__ ob,
            float* __restrict__ out)
{
    const int row = blockIdx.x;
    const size_t base = (size_t)row * 1024 + threadIdx.x * 4;
    float4 lsp = *(const float4*)(sp + base);
    u16 lg[4], lp[4], lw[4];
    *(uint2*)lg = *(const uint2*)(gt + base);
    *(uint2*)lp = *(const uint2*)(pm + base);
    *(uint2*)lw = *(const uint2*)(wm + base);
    float x[4];
    const float* lspp = (const float*)&lsp;
#pragma unroll
    for (int j = 0; j < 4; ++j) {
        float g = b2f(lg[j]);
        x[j] = lspp[j] + g * b2f(lp[j]) + (1.f - g) * b2f(lw[j]);
    }
    float s = x[0] + x[1] + x[2] + x[3];
    float q = x[0]*x[0] + x[1]*x[1] + x[2]*x[2] + x[3]*x[3];
#pragma unroll
    for (int off = 32; off; off >>= 1) { s += __shfl_xor(s, off); q += __shfl_xor(q, off); }
    __shared__ float sm[8];
    const int wave = threadIdx.x >> 6, lane = threadIdx.x & 63;
    if (lane == 0) { sm[wave] = s; sm[4 + wave] = q; }
    __syncthreads();
    s = sm[0] + sm[1] + sm[2] + sm[3];
    q = sm[4] + sm[5] + sm[6] + sm[7];
    const float mean = s * (1.f / 1024.f);
    const float var  = q * (1.f / 1024.f) - mean * mean;
    const float inv  = rsqrtf(var + 1e-5f);
    const int cb = threadIdx.x * 4;
    float4 o;
    float* op = (float*)&o;
#pragma unroll
    for (int j = 0; j < 4; ++j)
        op[j] = (x[j] - mean) * inv * og[cb + j] + ob[cb + j];
    *(float4*)(out + base) = o;
}

// Batched strided copy/convert: fp32->bf16 or bf16->bf16, 8 elems/thread.
struct CDesc { const void* src; u16* dst; int srcCols8; int dstStride; int dstOff; unsigned end; int isbf16; };
struct CArgs { CDesc d[16]; unsigned total; };

__global__ __launch_bounds__(256)
void multi_copy(CArgs ca)
{
    const unsigned idx = blockIdx.x * 256 + threadIdx.x;
    if (idx >= ca.total) return;
    int i = 0; unsigned start = 0;
    while (idx >= ca.d[i].end) { start = ca.d[i].end; ++i; }
    const CDesc cd = ca.d[i];
    const unsigned local = idx - start;
    const int r = local / cd.srcCols8;
    const int c = local % cd.srcCols8;
    u16 o[8];
    if (cd.isbf16) {
        *(uint4*)o = *(const uint4*)((const u16*)cd.src + ((size_t)r * cd.srcCols8 + c) * 8);
    } else {
        const float* s = (const float*)cd.src + ((size_t)r * cd.srcCols8 + c) * 8;
        const float4 a = *(const float4*)s;
        const float4 bq = *(const float4*)(s + 4);
        const float* ap = (const float*)&a;
        const float* bp = (const float*)&bq;
#pragma unroll
        for (int j = 0; j < 4; ++j) { o[j] = f2b(ap[j]); o[4 + j] = f2b(bp[j]); }
    }
    *(uint4*)(cd.dst + (size_t)r * cd.dstStride + cd.dstOff + (size_t)c * 8) = *(uint4*)o;
}

extern "C" void kernel_launch(void* const* d_in, const int* in_sizes, int n_in,
                              void* d_out, int out_size, void* d_ws, size_t ws_size,
                              hipStream_t stream)
{
    const float* s_prev = (const float*)d_in[0];
    const float* w_prev = (const float*)d_in[1];
    const float* p_prev = (const float*)d_in[2];
    const float* e_t    = (const float*)d_in[3];
    const float* c_t    = (const float*)d_in[4];
    const float* fw1    = (const float*)d_in[5];
    const float* fb1    = (const float*)d_in[6];
    const float* fln_g  = (const float*)d_in[7];
    const float* fln_b  = (const float*)d_in[8];
    const float* fw2    = (const float*)d_in[9];
    const float* fb2    = (const float*)d_in[10];
    const float* A_diag = (const float*)d_in[11];
    const float* A_U    = (const float*)d_in[12];
    const float* A_V    = (const float*)d_in[13];
    const float* amod_w = (const float*)d_in[14];
    const float* amod_b = (const float*)d_in[15];
    const float* bnet_w = (const float*)d_in[16];
    const float* bnet_b = (const float*)d_in[17];
    const float* pw1    = (const float*)d_in[18];
    const float* pb1    = (const float*)d_in[19];
    const float* pln_g  = (const float*)d_in[20];
    const float* pln_b  = (const float*)d_in[21];
    const float* pw2    = (const float*)d_in[22];
    const float* pb2    = (const float*)d_in[23];
    const float* pw3    = (const float*)d_in[24];
    const float* pb3    = (const float*)d_in[25];
    const float* gw     = (const float*)d_in[26];
    const float* gb     = (const float*)d_in[27];
    const float* uw     = (const float*)d_in[28];
    const float* up     = (const float*)d_in[29];
    const float* oln_g  = (const float*)d_in[30];
    const float* oln_b  = (const float*)d_in[31];

    float* out_s = (float*)d_out;                    // [8192,1024]
    float* out_w = out_s + (size_t)8192 * 1024;      // [8192,1024]
    float* out_p = out_w + (size_t)8192 * 1024;      // [8192,512]

    u16* ws = (u16*)d_ws;
    u16* FIN  = ws;                    // [8192,2560]; later PIN [8192,1536] at base
    u16* W_bf = ws + 12582912;         // [8192,1024]
    u16* H    = ws + 20971520;         // [8192,1024]; later P_bf [8192,512]
    u16* P_bf = H;
    u16* Z    = ws + 29360128;         // [8192,512]
    u16* G    = ws + 33554432;         // [8192,1024]
    u16* ACAT = ws + 41943040;         // [8192,2048]; later PM/WM
    u16* PM   = ACAT;
    u16* WM   = ACAT + 8388608;
    u16* WCAT = ws + 58720256;         // [1024,2048]
    u16* wb   = ws + 60817408;         // bf16 weights pool
    u16* fw1b  = wb;
    u16* gwb   = wb + 2621440;
    u16* fw2b  = wb + 5242880;
    u16* amodb = wb + 5767168;
    u16* pw1b  = wb + 6291456;
    u16* pw2b  = wb + 7864320;
    u16* pw3b  = wb + 8388608;
    u16* uwb   = wb + 8650752;
    u16* upb   = wb + 9699328;
    u16* AUb   = wb + 10223616;
    u16* AVb   = wb + 10485760;        // pool ends ws+10,747,904

    const dim3 blk(256);
    const dim3 blk512(512);

    // ---------- batch 1: weight cvts + FIN assembly + c_t->ACAT + bnet_w->WCAT
    {
        CArgs ca; unsigned cum = 0; int nd = 0;
        auto push = [&](const void* src, u16* dst, int cols8, int stride, int off,
                        int rows, int isbf) {
            cum += (unsigned)rows * cols8;
            ca.d[nd++] = CDesc{src, dst, cols8, stride, off, cum, isbf};
        };
        push(fw1,    fw1b,  320, 2560, 0,    1024, 0);
        push(gw,     gwb,   320, 2560, 0,    1024, 0);
        push(fw2,    fw2b,  128, 1024, 0,    512,  0);
        push(amod_w, amodb, 64,  512,  0,    1024, 0);
        push(pw1,    pw1b,  192, 1536, 0,    1024, 0);
        push(pw2,    pw2b,  128, 1024, 0,    512,  0);
        push(pw3,    pw3b,  64,  512,  0,    512,  0);
        push(uw,     uwb,   128, 1024, 0,    1024, 0);
        push(up,     upb,   64,  512,  0,    1024, 0);
        push(A_U,    AUb,   32,  256,  0,    1024, 0);
        push(A_V,    AVb,   32,  256,  0,    1024, 0);
        push(s_prev, FIN,   128, 2560, 0,    8192, 0);
        push(e_t,    FIN,   128, 2560, 1024, 8192, 0);
        push(c_t,    FIN,   64,  2560, 2048, 8192, 0);
        push(c_t,    ACAT,  64,  2048, 1024, 8192, 0);
        push(bnet_w, WCAT,  128, 2048, 1024, 1024, 0);
        ca.total = cum;
        multi_copy<<<dim3((cum + 255) / 256), blk, 0, stream>>>(ca);
    }

    // ---------- fused GEMM 1: fw1 (H) || gate (G) -> 512 blocks
    {
        GArgs ga;
        ga.d0 = GDesc{FIN, fw1b, fb1, nullptr, H, nullptr, 2560, 1024, 1024, 2560, EP_NONE,    32};
        ga.d1 = GDesc{FIN, gwb,  gb,  nullptr, G, nullptr, 2560, 1024, 1024, 2560, EP_SIGMOID, 32};
        ga.d2 = ga.d1; ga.s1 = 256; ga.s2 = 512;
        gemm_p<<<dim3(512), blk512, 0, stream>>>(ga);
    }
    ln1024<true><<<8192, blk, 0, stream>>>(H, fln_g, fln_b);

    // ---------- fused GEMM 2: fw2 (Z) || amod (ACAT) || A_base (WCAT) -> 416 blocks
    {
        GArgs ga;
        ga.d0 = GDesc{H,          fw2b,  fb2,     nullptr, Z,    nullptr, 1024, 512,  512,  1024, EP_NONE,     32};
        ga.d1 = GDesc{FIN + 2048, amodb, amod_b,  w_prev,  ACAT, nullptr, 2560, 2048, 1024, 512,  EP_TANH_MUL, 32};
        ga.d2 = GDesc{AUb,        AVb,   nullptr, A_diag,  WCAT, nullptr, 256,  2048, 1024, 256,  EP_DIAG,     4};
        ga.s1 = 128; ga.s2 = 384;
        gemm_p<<<dim3(416), blk512, 0, stream>>>(ga);
    }

    // ---------- batch 2: PIN = [p_prev || z || c_t] at FIN base; Z -> ACAT col 1536
    {
        CArgs ca; unsigned cum = 0; int nd = 0;
        auto push = [&](const void* src, u16* dst, int cols8, int stride, int off,
                        int rows, int isbf) {
            cum += (unsigned)rows * cols8;
            ca.d[nd++] = CDesc{src, dst, cols8, stride, off, cum, isbf};
        };
        push(p_prev, FIN,  64, 1536, 0,    8192, 0);
        push(Z,      FIN,  64, 1536, 512,  8192, 1);
        push(c_t,    FIN,  64, 1536, 1024, 8192, 0);
        push(Z,      ACAT, 64, 2048, 1536, 8192, 1);
        ca.total = cum;
        multi_copy<<<dim3((cum + 255) / 256), blk, 0, stream>>>(ca);
    }

    // ---------- fused GEMM 3: w_t (ACAT@WCAT^T) || pw1 (PIN) -> 512 blocks
    {
        GArgs ga;
        ga.d0 = GDesc{ACAT, WCAT, bnet_b, nullptr, W_bf, out_w,   2048, 1024, 1024, 2048, EP_NONE, 32};
        ga.d1 = GDesc{FIN,  pw1b, pb1,    nullptr, H,    nullptr, 1536, 1024, 1024, 1536, EP_NONE, 32};
        ga.d2 = ga.d1; ga.s1 = 256; ga.s2 = 512;
        gemm_p<<<dim3(512), blk512, 0, stream>>>(ga);
    }
    ln1024<true><<<8192, blk, 0, stream>>>(H, pln_g, pln_b);

    // ---------- fused GEMM 4: pw2 (H -> Z, relu) || uw (W_bf -> WM) -> 384 blocks
    {
        GArgs ga;
        ga.d0 = GDesc{H,    pw2b, pb2,     nullptr, Z,  nullptr, 1024, 512,  512,  1024, EP_RELU, 32};
        ga.d1 = GDesc{W_bf, uwb,  nullptr, nullptr, WM, nullptr, 1024, 1024, 1024, 1024, EP_NONE, 32};
        ga.d2 = ga.d1; ga.s1 = 128; ga.s2 = 384;
        gemm_p<<<dim3(384), blk512, 0, stream>>>(ga);
    }

    // ---------- pw3: p_t = p_prev + tanh(Z@pw3^T + pb3) -> P_bf + out_p
    {
        GArgs ga;
        ga.d0 = GDesc{Z, pw3b, pb3, p_prev, P_bf, out_p, 512, 512, 512, 512, EP_TANH_ADD, 32};
        ga.d1 = ga.d0; ga.d2 = ga.d0; ga.s1 = 128; ga.s2 = 128;
        gemm_p<<<dim3(128), blk512, 0, stream>>>(ga);
    }

    // ---------- up: pm = P_bf @ up^T -> PM
    {
        GArgs ga;
        ga.d0 = GDesc{P_bf, upb, nullptr, nullptr, PM, nullptr, 512, 1024, 1024, 512, EP_NONE, 32};
        ga.d1 = ga.d0; ga.d2 = ga.d0; ga.s1 = 256; ga.s2 = 256;
        gemm_p<<<dim3(256), blk512, 0, stream>>>(ga);
    }

    mix_ln<<<8192, blk, 0, stream>>>(s_prev, G, PM, WM, oln_g, oln_b, out_s);
}